// Round 16
// baseline (105.901 us; speedup 1.0000x reference)
//
#include <hip/hip_runtime.h>
#include <math.h>

// Problem constants: B=4, N=L=5, C=64, H=100, W=252
#define BB 4
#define NN 5
#define CC 64
#define HH 100
#define WW 252
#define HW (HH * WW)
#define TILE_W 64
#define NTW ((WW + TILE_W - 1) / TILE_W)   // 4 tiles per row
#define NXCD 8
#define PAD_B (64 * 1024)                   // guard pad before xt
#define PAD_A (128 * 1024)                  // guard pad after xt
#define XT_BYTES ((size_t)BB * NN * HH * WW * CC * 2)   // 64,512,000

typedef _Float16 h2v __attribute__((ext_vector_type(2)));
typedef _Float16 h8v __attribute__((ext_vector_type(8)));
typedef float    f4v __attribute__((ext_vector_type(4)));

// ---------- pass 1: transpose+quantize x (f32, BN,C,H,W) -> xt (f16, BN,H,W,C) ----------
// NT loads: x is dead after this pass; don't let 129MB of it evict xt from L2/L3.
// First 48 blocks also zero the guard pads (weight-0 taps read them; must be finite).
__global__ __launch_bounds__(256) void transpose_chw_hwc(
    const float* __restrict__ x, _Float16* __restrict__ xt, char* __restrict__ wsbase)
{
    if (blockIdx.x < 48) {                 // 48*256*16B = 196608 = PAD_B + PAD_A
        const int u = blockIdx.x * 256 + threadIdx.x;
        f4v z = {0.0f, 0.0f, 0.0f, 0.0f};
        char* dst = (u < PAD_B / 16)
                  ? wsbase + (size_t)u * 16
                  : wsbase + PAD_B + XT_BYTES + (size_t)(u - PAD_B / 16) * 16;
        *(f4v*)dst = z;
    }

    __shared__ float tile[CC][TILE_W + 1];
    const int blk = blockIdx.x;
    const int wt  = blk % NTW;
    const int h   = (blk / NTW) % HH;
    const int bn  = blk / (NTW * HH);
    const int w0  = wt * TILE_W;

    const int lane = threadIdx.x & 63;
    const int sub  = threadIdx.x >> 6;    // 0..3

#pragma unroll
    for (int it = 0; it < 16; ++it) {     // read coalesced along w (non-temporal)
        const int c = sub + 4 * it;
        const int w = w0 + lane;
        if (w < WW)
            tile[c][lane] = __builtin_nontemporal_load(
                &x[((size_t)(bn * CC + c) * HH + h) * WW + w]);
    }
    __syncthreads();
#pragma unroll
    for (int it = 0; it < 8; ++it) {      // write half2 units, coalesced along c
        const int unit = it * 256 + threadIdx.x;   // 0..2047
        const int px = unit >> 5;
        const int c2 = unit & 31;
        const int w  = w0 + px;
        if (w < WW) {
            h2v hv;
            hv[0] = (_Float16)tile[2 * c2 + 0][px];
            hv[1] = (_Float16)tile[2 * c2 + 1][px];
            *(h2v*)(xt + ((((size_t)bn * HH + h) * WW + w) * CC + 2 * c2)) = hv;
        }
    }
}

// ---------- pass 2: fp16 gather, packed-half2 blend (round-15 green structure) ----------
__global__ __launch_bounds__(512) void fuse_gather(
    const _Float16* __restrict__ xt,  // (BN, H, W, C) fp16 (padded alloc)
    const float* __restrict__ T,      // (B, L, L, 4, 4)
    float* __restrict__ out)          // (BN, C, H, W) fp32
{
    __shared__ float coord[NN][TILE_W][5];      // per (j, pixel): oc + 4 packed-h2 weights
    __shared__ float tile[TILE_W][CC + 1];      // per (pixel, channel) result

    // XCD chunked swizzle (bijective: 8000 % 8 == 0)
    const int cpx = gridDim.x / NXCD;
    const int blk = (blockIdx.x % NXCD) * cpx + blockIdx.x / NXCD;

    // decompose: b (2000 blocks each) -> hwt (i fastest inside)
    const int b   = blk / (NN * HH * NTW);
    const int r   = blk % (NN * HH * NTW);
    const int i   = r % NN;
    const int hwt = r / NN;           // 0..399
    const int wt  = hwt % NTW;
    const int h   = hwt / NTW;
    const int bi  = b * NN + i;
    const int w0  = wt * TILE_W;

    const int lane = threadIdx.x & 63;
    const int wv   = threadIdx.x >> 6;   // 0..7

    // ---- phase 0: waves 0..4 each compute one j's coords; lane = pixel.
    if (wv < NN) {
        const int jj = wv;
        const int w  = w0 + lane;
        const float gx = -1.0f + 2.0f * (float)w / (float)(WW - 1);
        const float gy = -1.0f + 2.0f * (float)h / (float)(HH - 1);
        const float sHW = (float)HH / (float)WW;
        const float sWH = (float)WW / (float)HH;
        const float sW  = 2.5f / (float)WW;
        const float sH  = 2.5f / (float)HH;

        const float* Tm = T + ((size_t)(b * NN + i) * NN + jj) * 16;
        const float m00 = Tm[0];
        const float m01 = Tm[1] * sHW;
        const float m02 = Tm[3] * sW;
        const float m10 = Tm[4] * sWH;
        const float m11 = Tm[5];
        const float m12 = Tm[7] * sH;

        const float cx = __builtin_fmaf(m00, gx, __builtin_fmaf(m01, gy, m02));
        const float cy = __builtin_fmaf(m10, gx, __builtin_fmaf(m11, gy, m12));
        const float ix = (cx + 1.0f) * (0.5f * (float)(WW - 1));
        const float iy = (cy + 1.0f) * (0.5f * (float)(HH - 1));

        const float x0f = floorf(ix);
        const float y0f = floorf(iy);
        const int x0 = (int)x0f, y0 = (int)y0f;
        const int x1 = x0 + 1,  y1 = y0 + 1;

        const float wx1 = ix - x0f, wy1 = iy - y0f;
        const float wx0 = 1.0f - wx1, wy0 = 1.0f - wy1;

        const float v00 = (x0 >= 0 && x0 < WW && y0 >= 0 && y0 < HH) ? 1.0f : 0.0f;
        const float v01 = (x1 >= 0 && x1 < WW && y0 >= 0 && y0 < HH) ? 1.0f : 0.0f;
        const float v10 = (x0 >= 0 && x0 < WW && y1 >= 0 && y1 < HH) ? 1.0f : 0.0f;
        const float v11 = (x1 >= 0 && x1 < WW && y1 >= 0 && y1 < HH) ? 1.0f : 0.0f;

        // address-safety clamp only (affected taps always carry weight 0)
        const int x0s = min(max(x0, -1), WW);
        const int y0s = min(max(y0, -1), HH);
        const int oc  = (y0s * WW + x0s) * CC;

        // pack each weight as a half2 splat
        const _Float16 h00 = (_Float16)(wy0 * wx0 * v00);
        const _Float16 h01 = (_Float16)(wy0 * wx1 * v01);
        const _Float16 h10 = (_Float16)(wy1 * wx0 * v10);
        const _Float16 h11 = (_Float16)(wy1 * wx1 * v11);

        float* cd = coord[jj][lane];
        cd[0] = __int_as_float(oc);
        h2v p00 = {h00, h00}; cd[1] = __builtin_bit_cast(float, p00);
        h2v p01 = {h01, h01}; cd[2] = __builtin_bit_cast(float, p01);
        h2v p10 = {h10, h10}; cd[3] = __builtin_bit_cast(float, p10);
        h2v p11 = {h11, h11}; cd[4] = __builtin_bit_cast(float, p11);
    }
    __syncthreads();

    // ---- phase A: wave wv owns pixels wv*8..wv*8+7; 8 lanes per pixel,
    // 8 channels per lane; blend fully in packed fp16 (pk_fma / pk_max).
    {
        const int g   = lane >> 3;         // pixel within wave's 8
        const int ch8 = (lane & 7) * 8;    // channel start
        const int p   = wv * 8 + g;

        if (w0 + p < WW) {
            const _Float16 NEGINF = (_Float16)(-INFINITY);
            h2v a0 = {NEGINF, NEGINF}, a1 = a0, a2 = a0, a3 = a0;

#pragma unroll
            for (int j = 0; j < NN; ++j) {
                const float* cd = coord[j][p];
                const int oc  = __float_as_int(cd[0]);
                const h2v w00 = __builtin_bit_cast(h2v, cd[1]);
                const h2v w01 = __builtin_bit_cast(h2v, cd[2]);
                const h2v w10 = __builtin_bit_cast(h2v, cd[3]);
                const h2v w11 = __builtin_bit_cast(h2v, cd[4]);

                const _Float16* base0 = xt + (size_t)(b * NN + j) * HW * CC
                                           + (long)oc + ch8;
                const _Float16* base1 = base0 + (long)WW * CC;

                const h8v t00 = *(const h8v*)(base0);
                const h8v t01 = *(const h8v*)(base0 + CC);
                const h8v t10 = *(const h8v*)(base1);
                const h8v t11 = *(const h8v*)(base1 + CC);

#define CHUNK(k, acc)                                                          \
                {                                                              \
                    h2v c00 = __builtin_shufflevector(t00, t00, 2*k, 2*k+1);   \
                    h2v c01 = __builtin_shufflevector(t01, t01, 2*k, 2*k+1);   \
                    h2v c10 = __builtin_shufflevector(t10, t10, 2*k, 2*k+1);   \
                    h2v c11 = __builtin_shufflevector(t11, t11, 2*k, 2*k+1);   \
                    h2v s = c11 * w11;                                         \
                    s = c10 * w10 + s;                                         \
                    s = c01 * w01 + s;                                         \
                    s = c00 * w00 + s;                                         \
                    acc = __builtin_elementwise_max(acc, s);                   \
                }
                CHUNK(0, a0) CHUNK(1, a1) CHUNK(2, a2) CHUNK(3, a3)
#undef CHUNK
            }
            float* tp = &tile[p][ch8];
            tp[0] = (float)a0[0]; tp[1] = (float)a0[1];
            tp[2] = (float)a1[0]; tp[3] = (float)a1[1];
            tp[4] = (float)a2[0]; tp[5] = (float)a2[1];
            tp[6] = (float)a3[0]; tp[7] = (float)a3[1];
        }
    }
    __syncthreads();

    // ---- phase B: non-temporal f4v stores along w (out is never re-read;
    // keep the per-XCD L2 for the live xt tap bands).
#pragma unroll
    for (int rep = 0; rep < 2; ++rep) {
        const int unit = threadIdx.x + 512 * rep;   // 0..1023
        const int q = unit & 15;                    // w-quad
        const int c = unit >> 4;                    // 0..63
        const int w = w0 + 4 * q;
        if (w < WW) {
            f4v v;
            v.x = tile[4 * q + 0][c];
            v.y = tile[4 * q + 1][c];
            v.z = tile[4 * q + 2][c];
            v.w = tile[4 * q + 3][c];
            __builtin_nontemporal_store(v,
                (f4v*)(out + ((size_t)bi * CC + c) * HW + h * WW + w));
        }
    }
}

// ---------- fallback (round-4 kernel) if workspace is too small ----------
#define CG 16
#define NCG (CC / CG)
__global__ __launch_bounds__(256, 4) void where2comm_fuse_fallback(
    const float* __restrict__ x, const float* __restrict__ T,
    float* __restrict__ out)
{
    const int tid = blockIdx.x * blockDim.x + threadIdx.x;
    const int total = BB * NN * HW * NCG;
    if (tid >= total) return;
    const int w = tid % WW;
    int t2 = tid / WW;
    const int h = t2 % HH;
    t2 /= HH;
    const int bi = t2 % (BB * NN);
    const int cg = t2 / (BB * NN);
    const int b = bi / NN, i = bi % NN;
    const float gx = -1.0f + 2.0f * (float)w / (float)(WW - 1);
    const float gy = -1.0f + 2.0f * (float)h / (float)(HH - 1);
    float acc[CG];
#pragma unroll
    for (int c = 0; c < CG; ++c) acc[c] = -INFINITY;
    const float sHW = (float)HH / (float)WW, sWH = (float)WW / (float)HH;
    const float sW = 2.5f / (float)WW, sH = 2.5f / (float)HH;
    for (int j = 0; j < NN; ++j) {
        const float* Tm = T + ((size_t)(b * NN + i) * NN + j) * 16;
        const float m00 = Tm[0], m01 = Tm[1] * sHW, m02 = Tm[3] * sW;
        const float m10 = Tm[4] * sWH, m11 = Tm[5], m12 = Tm[7] * sH;
        const float cx = __builtin_fmaf(m00, gx, __builtin_fmaf(m01, gy, m02));
        const float cy = __builtin_fmaf(m10, gx, __builtin_fmaf(m11, gy, m12));
        const float ix = (cx + 1.0f) * (0.5f * (float)(WW - 1));
        const float iy = (cy + 1.0f) * (0.5f * (float)(HH - 1));
        const float x0f = floorf(ix), y0f = floorf(iy);
        const int x0 = (int)x0f, y0 = (int)y0f, x1 = x0 + 1, y1 = y0 + 1;
        const float wx1 = ix - x0f, wy1 = iy - y0f;
        const float wx0 = 1.0f - wx1, wy0 = 1.0f - wy1;
        const float v00 = (x0 >= 0 && x0 < WW && y0 >= 0 && y0 < HH) ? 1.0f : 0.0f;
        const float v01 = (x1 >= 0 && x1 < WW && y0 >= 0 && y0 < HH) ? 1.0f : 0.0f;
        const float v10 = (x0 >= 0 && x0 < WW && y1 >= 0 && y1 < HH) ? 1.0f : 0.0f;
        const float v11 = (x1 >= 0 && x1 < WW && y1 >= 0 && y1 < HH) ? 1.0f : 0.0f;
        const float w00 = wy0 * wx0 * v00, w01 = wy0 * wx1 * v01;
        const float w10 = wy1 * wx0 * v10, w11 = wy1 * wx1 * v11;
        const int x0c = min(max(x0, 0), WW - 1), x1c = min(max(x1, 0), WW - 1);
        const int y0c = min(max(y0, 0), HH - 1), y1c = min(max(y1, 0), HH - 1);
        const int o00 = y0c * WW + x0c, o01 = y0c * WW + x1c;
        const int o10 = y1c * WW + x0c, o11 = y1c * WW + x1c;
        const float* p = x + ((size_t)(b * NN + j) * CC + cg * CG) * HW;
        float t00[CG], t01[CG], t10[CG], t11[CG];
#pragma unroll
        for (int c = 0; c < CG; ++c) {
            const float* pc = p + (size_t)c * HW;
            t00[c] = pc[o00]; t01[c] = pc[o01]; t10[c] = pc[o10]; t11[c] = pc[o11];
        }
#pragma unroll
        for (int c = 0; c < CG; ++c) {
            const float s = __builtin_fmaf(w00, t00[c], __builtin_fmaf(w01, t01[c],
                            __builtin_fmaf(w10, t10[c], w11 * t11[c])));
            acc[c] = fmaxf(acc[c], s);
        }
    }
    float* op = out + ((size_t)bi * CC + cg * CG) * HW + h * WW + w;
#pragma unroll
    for (int c = 0; c < CG; ++c) op[(size_t)c * HW] = acc[c];
}

extern "C" void kernel_launch(void* const* d_in, const int* in_sizes, int n_in,
                              void* d_out, int out_size, void* d_ws, size_t ws_size,
                              hipStream_t stream) {
    const float* x = (const float*)d_in[0];
    const float* T = (const float*)d_in[3];
    float* out = (float*)d_out;

    if (ws_size >= PAD_B + XT_BYTES + PAD_A) {
        _Float16* xt = (_Float16*)((char*)d_ws + PAD_B);
        const int grid1 = BB * NN * HH * NTW;   // 8000
        transpose_chw_hwc<<<grid1, 256, 0, stream>>>(x, xt, (char*)d_ws);
        const int grid2 = BB * NN * HH * NTW;   // 8000
        fuse_gather<<<grid2, 512, 0, stream>>>(xt, T, out);
    } else {
        const int total = BB * NN * HW * NCG;
        where2comm_fuse_fallback<<<(total + 255) / 256, 256, 0, stream>>>(x, T, out);
    }
}

// Round 19
// 100.404 us; speedup vs baseline: 1.0548x; 1.0548x over previous
//
#include <hip/hip_runtime.h>
#include <math.h>

// Problem constants: B=4, N=L=5, C=64, H=100, W=252
#define BB 4
#define NN 5
#define CC 64
#define HH 100
#define WW 252
#define HW (HH * WW)
#define TILE_W 64
#define NTW ((WW + TILE_W - 1) / TILE_W)   // 4 tiles per row
#define NXCD 8
#define PAD_B (64 * 1024)                   // guard pad before xt
#define PAD_A (128 * 1024)                  // guard pad after xt
#define XT_BYTES ((size_t)BB * NN * HH * WW * CC * 2)   // 64,512,000

typedef _Float16 h2v __attribute__((ext_vector_type(2)));
typedef _Float16 h8v __attribute__((ext_vector_type(8)));
typedef float    f4v __attribute__((ext_vector_type(4)));

// ---------- pass 1: transpose+quantize x (f32, BN,C,H,W) -> xt (f16, BN,H,W,C) ----------
// First 48 blocks additionally zero the guard pads so weight-0 taps always read
// finite values (first-call d_ws is uninitialized; NaN bits would be fragile).
__global__ __launch_bounds__(256) void transpose_chw_hwc(
    const float* __restrict__ x, _Float16* __restrict__ xt, char* __restrict__ wsbase)
{
    if (blockIdx.x < 48) {                 // 48*256*16B = 196608 = PAD_B + PAD_A
        const int u = blockIdx.x * 256 + threadIdx.x;
        f4v z = {0.0f, 0.0f, 0.0f, 0.0f};
        char* dst = (u < PAD_B / 16)
                  ? wsbase + (size_t)u * 16
                  : wsbase + PAD_B + XT_BYTES + (size_t)(u - PAD_B / 16) * 16;
        *(f4v*)dst = z;
    }

    __shared__ float tile[CC][TILE_W + 1];
    const int blk = blockIdx.x;
    const int wt  = blk % NTW;
    const int h   = (blk / NTW) % HH;
    const int bn  = blk / (NTW * HH);
    const int w0  = wt * TILE_W;

    const int lane = threadIdx.x & 63;
    const int sub  = threadIdx.x >> 6;    // 0..3

#pragma unroll
    for (int it = 0; it < 16; ++it) {     // read coalesced along w
        const int c = sub + 4 * it;
        const int w = w0 + lane;
        if (w < WW)
            tile[c][lane] = x[((size_t)(bn * CC + c) * HH + h) * WW + w];
    }
    __syncthreads();
#pragma unroll
    for (int it = 0; it < 8; ++it) {      // write half2 units, coalesced along c
        const int unit = it * 256 + threadIdx.x;   // 0..2047
        const int px = unit >> 5;
        const int c2 = unit & 31;
        const int w  = w0 + px;
        if (w < WW) {
            h2v hv;
            hv[0] = (_Float16)tile[2 * c2 + 0][px];
            hv[1] = (_Float16)tile[2 * c2 + 1][px];
            *(h2v*)(xt + ((((size_t)bn * HH + h) * WW + w) * CC + 2 * c2)) = hv;
        }
    }
}

// ---------- pass 2: fp16 gather, packed-half2 blend (round-15 green structure) ----------
__global__ __launch_bounds__(512) void fuse_gather(
    const _Float16* __restrict__ xt,  // (BN, H, W, C) fp16 (padded alloc)
    const float* __restrict__ T,      // (B, L, L, 4, 4)
    float* __restrict__ out)          // (BN, C, H, W) fp32
{
    __shared__ float coord[NN][TILE_W][5];      // per (j, pixel): oc + 4 packed-h2 weights
    __shared__ float tile[TILE_W][CC + 1];      // per (pixel, channel) result

    // XCD chunked swizzle (bijective: 8000 % 8 == 0)
    const int cpx = gridDim.x / NXCD;
    const int blk = (blockIdx.x % NXCD) * cpx + blockIdx.x / NXCD;

    // decompose: b (2000 blocks each) -> hwt (i fastest inside)
    const int b   = blk / (NN * HH * NTW);
    const int r   = blk % (NN * HH * NTW);
    const int i   = r % NN;
    const int hwt = r / NN;           // 0..399
    const int wt  = hwt % NTW;
    const int h   = hwt / NTW;
    const int bi  = b * NN + i;
    const int w0  = wt * TILE_W;

    const int lane = threadIdx.x & 63;
    const int wv   = threadIdx.x >> 6;   // 0..7

    // ---- phase 0: waves 0..4 each compute one j's coords; lane = pixel.
    if (wv < NN) {
        const int jj = wv;
        const int w  = w0 + lane;
        const float gx = -1.0f + 2.0f * (float)w / (float)(WW - 1);
        const float gy = -1.0f + 2.0f * (float)h / (float)(HH - 1);
        const float sHW = (float)HH / (float)WW;
        const float sWH = (float)WW / (float)HH;
        const float sW  = 2.5f / (float)WW;
        const float sH  = 2.5f / (float)HH;

        const float* Tm = T + ((size_t)(b * NN + i) * NN + jj) * 16;
        const float m00 = Tm[0];
        const float m01 = Tm[1] * sHW;
        const float m02 = Tm[3] * sW;
        const float m10 = Tm[4] * sWH;
        const float m11 = Tm[5];
        const float m12 = Tm[7] * sH;

        const float cx = __builtin_fmaf(m00, gx, __builtin_fmaf(m01, gy, m02));
        const float cy = __builtin_fmaf(m10, gx, __builtin_fmaf(m11, gy, m12));
        const float ix = (cx + 1.0f) * (0.5f * (float)(WW - 1));
        const float iy = (cy + 1.0f) * (0.5f * (float)(HH - 1));

        const float x0f = floorf(ix);
        const float y0f = floorf(iy);
        const int x0 = (int)x0f, y0 = (int)y0f;
        const int x1 = x0 + 1,  y1 = y0 + 1;

        const float wx1 = ix - x0f, wy1 = iy - y0f;
        const float wx0 = 1.0f - wx1, wy0 = 1.0f - wy1;

        const float v00 = (x0 >= 0 && x0 < WW && y0 >= 0 && y0 < HH) ? 1.0f : 0.0f;
        const float v01 = (x1 >= 0 && x1 < WW && y0 >= 0 && y0 < HH) ? 1.0f : 0.0f;
        const float v10 = (x0 >= 0 && x0 < WW && y1 >= 0 && y1 < HH) ? 1.0f : 0.0f;
        const float v11 = (x1 >= 0 && x1 < WW && y1 >= 0 && y1 < HH) ? 1.0f : 0.0f;

        // address-safety clamp only (affected taps always carry weight 0)
        const int x0s = min(max(x0, -1), WW);
        const int y0s = min(max(y0, -1), HH);
        const int oc  = (y0s * WW + x0s) * CC;

        // pack each weight as a half2 splat
        const _Float16 h00 = (_Float16)(wy0 * wx0 * v00);
        const _Float16 h01 = (_Float16)(wy0 * wx1 * v01);
        const _Float16 h10 = (_Float16)(wy1 * wx0 * v10);
        const _Float16 h11 = (_Float16)(wy1 * wx1 * v11);

        float* cd = coord[jj][lane];
        cd[0] = __int_as_float(oc);
        h2v p00 = {h00, h00}; cd[1] = __builtin_bit_cast(float, p00);
        h2v p01 = {h01, h01}; cd[2] = __builtin_bit_cast(float, p01);
        h2v p10 = {h10, h10}; cd[3] = __builtin_bit_cast(float, p10);
        h2v p11 = {h11, h11}; cd[4] = __builtin_bit_cast(float, p11);
    }
    __syncthreads();

    // ---- phase A: wave wv owns pixels wv*8..wv*8+7; 8 lanes per pixel,
    // 8 channels per lane; blend fully in packed fp16 (pk_fma / pk_max).
    {
        const int g   = lane >> 3;         // pixel within wave's 8
        const int ch8 = (lane & 7) * 8;    // channel start
        const int p   = wv * 8 + g;

        if (w0 + p < WW) {
            const _Float16 NEGINF = (_Float16)(-INFINITY);
            h2v a0 = {NEGINF, NEGINF}, a1 = a0, a2 = a0, a3 = a0;

#pragma unroll
            for (int j = 0; j < NN; ++j) {
                const float* cd = coord[j][p];
                const int oc  = __float_as_int(cd[0]);
                const h2v w00 = __builtin_bit_cast(h2v, cd[1]);
                const h2v w01 = __builtin_bit_cast(h2v, cd[2]);
                const h2v w10 = __builtin_bit_cast(h2v, cd[3]);
                const h2v w11 = __builtin_bit_cast(h2v, cd[4]);

                const _Float16* base0 = xt + (size_t)(b * NN + j) * HW * CC
                                           + (long)oc + ch8;
                const _Float16* base1 = base0 + (long)WW * CC;

                const h8v t00 = *(const h8v*)(base0);
                const h8v t01 = *(const h8v*)(base0 + CC);
                const h8v t10 = *(const h8v*)(base1);
                const h8v t11 = *(const h8v*)(base1 + CC);

#define CHUNK(k, acc)                                                          \
                {                                                              \
                    h2v c00 = __builtin_shufflevector(t00, t00, 2*k, 2*k+1);   \
                    h2v c01 = __builtin_shufflevector(t01, t01, 2*k, 2*k+1);   \
                    h2v c10 = __builtin_shufflevector(t10, t10, 2*k, 2*k+1);   \
                    h2v c11 = __builtin_shufflevector(t11, t11, 2*k, 2*k+1);   \
                    h2v s = c11 * w11;                                         \
                    s = c10 * w10 + s;                                         \
                    s = c01 * w01 + s;                                         \
                    s = c00 * w00 + s;                                         \
                    acc = __builtin_elementwise_max(acc, s);                   \
                }
                CHUNK(0, a0) CHUNK(1, a1) CHUNK(2, a2) CHUNK(3, a3)
#undef CHUNK
            }
            float* tp = &tile[p][ch8];
            tp[0] = (float)a0[0]; tp[1] = (float)a0[1];
            tp[2] = (float)a1[0]; tp[3] = (float)a1[1];
            tp[4] = (float)a2[0]; tp[5] = (float)a2[1];
            tp[6] = (float)a3[0]; tp[7] = (float)a3[1];
        }
    }
    __syncthreads();

    // ---- phase B: float4 stores along w. unit = (c, w-quad); 2 units/thread.
#pragma unroll
    for (int rep = 0; rep < 2; ++rep) {
        const int unit = threadIdx.x + 512 * rep;   // 0..1023
        const int q = unit & 15;                    // w-quad
        const int c = unit >> 4;                    // 0..63
        const int w = w0 + 4 * q;
        if (w < WW) {
            float4 v;
            v.x = tile[4 * q + 0][c];
            v.y = tile[4 * q + 1][c];
            v.z = tile[4 * q + 2][c];
            v.w = tile[4 * q + 3][c];
            *(float4*)(out + ((size_t)bi * CC + c) * HW + h * WW + w) = v;
        }
    }
}

// ---------- fallback (round-4 kernel) if workspace is too small ----------
#define CG 16
#define NCG (CC / CG)
__global__ __launch_bounds__(256, 4) void where2comm_fuse_fallback(
    const float* __restrict__ x, const float* __restrict__ T,
    float* __restrict__ out)
{
    const int tid = blockIdx.x * blockDim.x + threadIdx.x;
    const int total = BB * NN * HW * NCG;
    if (tid >= total) return;
    const int w = tid % WW;
    int t2 = tid / WW;
    const int h = t2 % HH;
    t2 /= HH;
    const int bi = t2 % (BB * NN);
    const int cg = t2 / (BB * NN);
    const int b = bi / NN, i = bi % NN;
    const float gx = -1.0f + 2.0f * (float)w / (float)(WW - 1);
    const float gy = -1.0f + 2.0f * (float)h / (float)(HH - 1);
    float acc[CG];
#pragma unroll
    for (int c = 0; c < CG; ++c) acc[c] = -INFINITY;
    const float sHW = (float)HH / (float)WW, sWH = (float)WW / (float)HH;
    const float sW = 2.5f / (float)WW, sH = 2.5f / (float)HH;
    for (int j = 0; j < NN; ++j) {
        const float* Tm = T + ((size_t)(b * NN + i) * NN + j) * 16;
        const float m00 = Tm[0], m01 = Tm[1] * sHW, m02 = Tm[3] * sW;
        const float m10 = Tm[4] * sWH, m11 = Tm[5], m12 = Tm[7] * sH;
        const float cx = __builtin_fmaf(m00, gx, __builtin_fmaf(m01, gy, m02));
        const float cy = __builtin_fmaf(m10, gx, __builtin_fmaf(m11, gy, m12));
        const float ix = (cx + 1.0f) * (0.5f * (float)(WW - 1));
        const float iy = (cy + 1.0f) * (0.5f * (float)(HH - 1));
        const float x0f = floorf(ix), y0f = floorf(iy);
        const int x0 = (int)x0f, y0 = (int)y0f, x1 = x0 + 1, y1 = y0 + 1;
        const float wx1 = ix - x0f, wy1 = iy - y0f;
        const float wx0 = 1.0f - wx1, wy0 = 1.0f - wy1;
        const float v00 = (x0 >= 0 && x0 < WW && y0 >= 0 && y0 < HH) ? 1.0f : 0.0f;
        const float v01 = (x1 >= 0 && x1 < WW && y0 >= 0 && y0 < HH) ? 1.0f : 0.0f;
        const float v10 = (x0 >= 0 && x0 < WW && y1 >= 0 && y1 < HH) ? 1.0f : 0.0f;
        const float v11 = (x1 >= 0 && x1 < WW && y1 >= 0 && y1 < HH) ? 1.0f : 0.0f;
        const float w00 = wy0 * wx0 * v00, w01 = wy0 * wx1 * v01;
        const float w10 = wy1 * wx0 * v10, w11 = wy1 * wx1 * v11;
        const int x0c = min(max(x0, 0), WW - 1), x1c = min(max(x1, 0), WW - 1);
        const int y0c = min(max(y0, 0), HH - 1), y1c = min(max(y1, 0), HH - 1);
        const int o00 = y0c * WW + x0c, o01 = y0c * WW + x1c;
        const int o10 = y1c * WW + x0c, o11 = y1c * WW + x1c;
        const float* p = x + ((size_t)(b * NN + j) * CC + cg * CG) * HW;
        float t00[CG], t01[CG], t10[CG], t11[CG];
#pragma unroll
        for (int c = 0; c < CG; ++c) {
            const float* pc = p + (size_t)c * HW;
            t00[c] = pc[o00]; t01[c] = pc[o01]; t10[c] = pc[o10]; t11[c] = pc[o11];
        }
#pragma unroll
        for (int c = 0; c < CG; ++c) {
            const float s = __builtin_fmaf(w00, t00[c], __builtin_fmaf(w01, t01[c],
                            __builtin_fmaf(w10, t10[c], w11 * t11[c])));
            acc[c] = fmaxf(acc[c], s);
        }
    }
    float* op = out + ((size_t)bi * CC + cg * CG) * HW + h * WW + w;
#pragma unroll
    for (int c = 0; c < CG; ++c) op[(size_t)c * HW] = acc[c];
}

extern "C" void kernel_launch(void* const* d_in, const int* in_sizes, int n_in,
                              void* d_out, int out_size, void* d_ws, size_t ws_size,
                              hipStream_t stream) {
    const float* x = (const float*)d_in[0];
    const float* T = (const float*)d_in[3];
    float* out = (float*)d_out;

    if (ws_size >= PAD_B + XT_BYTES + PAD_A) {
        _Float16* xt = (_Float16*)((char*)d_ws + PAD_B);
        const int grid1 = BB * NN * HH * NTW;   // 8000
        transpose_chw_hwc<<<grid1, 256, 0, stream>>>(x, xt, (char*)d_ws);
        const int grid2 = BB * NN * HH * NTW;   // 8000
        fuse_gather<<<grid2, 512, 0, stream>>>(xt, T, out);
    } else {
        const int total = BB * NN * HW * NCG;
        where2comm_fuse_fallback<<<(total + 255) / 256, 256, 0, stream>>>(x, T, out);
    }
}